// Round 6
// baseline (16077.686 us; speedup 1.0000x reference)
//
#include <hip/hip_runtime.h>

// Problem constants (b=8, n=1024, m=1024, d=256, RHO=1, LAMBDA=0.1, 50 iters)
// ADMM box-QP via Woodbury on A = I + 2 Vs Vs^T  (Vs = V / 1024).
//   state e (f64):  z = clip(e), s = 2z - e
//   w  = W1 @ s - Pvp            (fp32, K=1024)   W1 = M Vs^T, Pvp = M Vs^T P
//   e' = clip(e) - P - (2/1024) * (V @ w)   (fp32 K=256 + f64 elementwise)
// Persistent kernel: block owns 8 columns for all 50 iters (2 blocks/CU via
// 60KB LDS). R6 fix: __launch_bounds__(512,2) -> 128-VGPR cap, e-state stays
// in registers (R5's (512,4) forced a 64-VGPR cap -> e spilled to scratch,
// 756MB HBM write traffic). Math bitwise-identical to rounds 3/5.

__device__ __forceinline__ double clip01(double v) { return fmin(fmax(v, 0.0), 1.0); }

// ---------------- NT GEMM, f64 accumulate: C = (TC)(alpha * A@B^T + c0) ----------
template <typename TA, typename TC>
__global__ __launch_bounds__(256) void k_gemm_nt(
    const TA* __restrict__ Ag, const float* __restrict__ Bg, TC* __restrict__ Cg,
    int M, int N, int K, long sA, long sB, long sC, double alpha, double c0)
{
  const TA* A = Ag + (long)blockIdx.z * sA;
  const float* B = Bg + (long)blockIdx.z * sB;
  TC* C = Cg + (long)blockIdx.z * sC;
  const int m0 = blockIdx.x * 64, n0 = blockIdx.y * 64;
  const int tid = threadIdx.x;
  __shared__ double As[32][68];
  __shared__ double Bs[32][68];
  const int tx = tid & 15, ty = tid >> 4;
  const int r = tid >> 2, kq = (tid & 3) * 8;
  double acc[4][4] = {};
  for (int k0 = 0; k0 < K; k0 += 32) {
    if constexpr (sizeof(TA) == 4) {
      const float4* ap = reinterpret_cast<const float4*>(A + (size_t)(m0 + r) * K + k0 + kq);
      float4 a0 = ap[0], a1 = ap[1];
      As[kq+0][r] = a0.x; As[kq+1][r] = a0.y; As[kq+2][r] = a0.z; As[kq+3][r] = a0.w;
      As[kq+4][r] = a1.x; As[kq+5][r] = a1.y; As[kq+6][r] = a1.z; As[kq+7][r] = a1.w;
    } else {
      const double2* ap = reinterpret_cast<const double2*>(A + (size_t)(m0 + r) * K + k0 + kq);
      double2 a0 = ap[0], a1 = ap[1], a2 = ap[2], a3 = ap[3];
      As[kq+0][r] = a0.x; As[kq+1][r] = a0.y; As[kq+2][r] = a1.x; As[kq+3][r] = a1.y;
      As[kq+4][r] = a2.x; As[kq+5][r] = a2.y; As[kq+6][r] = a3.x; As[kq+7][r] = a3.y;
    }
    {
      const float4* bp = reinterpret_cast<const float4*>(B + (size_t)(n0 + r) * K + k0 + kq);
      float4 b0 = bp[0], b1 = bp[1];
      Bs[kq+0][r] = b0.x; Bs[kq+1][r] = b0.y; Bs[kq+2][r] = b0.z; Bs[kq+3][r] = b0.w;
      Bs[kq+4][r] = b1.x; Bs[kq+5][r] = b1.y; Bs[kq+6][r] = b1.z; Bs[kq+7][r] = b1.w;
    }
    __syncthreads();
#pragma unroll
    for (int kk = 0; kk < 32; ++kk) {
      double a_[4], b_[4];
#pragma unroll
      for (int i = 0; i < 4; ++i) a_[i] = As[kk][ty * 4 + i];
#pragma unroll
      for (int j = 0; j < 4; ++j) b_[j] = Bs[kk][tx * 4 + j];
#pragma unroll
      for (int i = 0; i < 4; ++i)
#pragma unroll
        for (int j = 0; j < 4; ++j) acc[i][j] = fma(a_[i], b_[j], acc[i][j]);
    }
    __syncthreads();
  }
#pragma unroll
  for (int i = 0; i < 4; ++i) {
    int row = m0 + ty * 4 + i;
#pragma unroll
    for (int j = 0; j < 4; ++j)
      C[(size_t)row * N + n0 + tx * 4 + j] = (TC)(alpha * acc[i][j] + c0);
  }
}

// ---------------- TN GEMM, f64 accumulate: C[MxN] = scale * A^T @ B -------------
template <typename TB>
__global__ __launch_bounds__(256) void k_gemm_tn(
    const float* __restrict__ Ag, const TB* __restrict__ Bg, double* __restrict__ Cg,
    int M, int N, int K, long sA, long sB, long sC, double scale)
{
  const float* A = Ag + (long)blockIdx.z * sA;
  const TB* B = Bg + (long)blockIdx.z * sB;
  double* C = Cg + (long)blockIdx.z * sC;
  const int m0 = blockIdx.x * 64, n0 = blockIdx.y * 64;
  const int tid = threadIdx.x;
  __shared__ float As[16][68];
  __shared__ double Bs[16][68];
  const int tx = tid & 15, ty = tid >> 4;
  const int kk = tid >> 4, c4 = (tid & 15) * 4;
  double acc[4][4] = {};
  for (int k0 = 0; k0 < K; k0 += 16) {
    float4 av = *reinterpret_cast<const float4*>(A + (size_t)(k0 + kk) * M + m0 + c4);
    *reinterpret_cast<float4*>(&As[kk][c4]) = av;
    if constexpr (sizeof(TB) == 4) {
      float4 bv = *reinterpret_cast<const float4*>(B + (size_t)(k0 + kk) * N + n0 + c4);
      Bs[kk][c4 + 0] = bv.x; Bs[kk][c4 + 1] = bv.y; Bs[kk][c4 + 2] = bv.z; Bs[kk][c4 + 3] = bv.w;
    } else {
      const double2* bp = reinterpret_cast<const double2*>(B + (size_t)(k0 + kk) * N + n0 + c4);
      double2 b0 = bp[0], b1 = bp[1];
      *reinterpret_cast<double2*>(&Bs[kk][c4]) = b0;
      *reinterpret_cast<double2*>(&Bs[kk][c4 + 2]) = b1;
    }
    __syncthreads();
#pragma unroll
    for (int k = 0; k < 16; ++k) {
      double a_[4], b_[4];
#pragma unroll
      for (int i = 0; i < 4; ++i) a_[i] = (double)As[k][ty * 4 + i];
#pragma unroll
      for (int j = 0; j < 4; ++j) b_[j] = Bs[k][tx * 4 + j];
#pragma unroll
      for (int i = 0; i < 4; ++i)
#pragma unroll
        for (int j = 0; j < 4; ++j) acc[i][j] = fma(a_[i], b_[j], acc[i][j]);
    }
    __syncthreads();
  }
#pragma unroll
  for (int i = 0; i < 4; ++i) {
    int row = m0 + ty * 4 + i;
#pragma unroll
    for (int j = 0; j < 4; ++j)
      C[(size_t)row * N + n0 + tx * 4 + j] = scale * acc[i][j];
  }
}

// ---------------- Ad = I + 2G, X0 = I - 2G --------------------------------------
__global__ __launch_bounds__(256) void k_adx0(const double* __restrict__ G,
                                              double* __restrict__ Ad, double* __restrict__ X)
{
  size_t idx = (size_t)blockIdx.x * 256 + threadIdx.x;
  double g = G[idx];
  int ij = (int)(idx & 65535);
  double dg = ((ij >> 8) == (ij & 255)) ? 1.0 : 0.0;
  Ad[idx] = dg + 2.0 * g;
  X[idx] = dg - 2.0 * g;
}

// ---------------- small f64 NN GEMM: C = alpha*A@B + beta*Xin -------------------
template <bool F32OUT>
__global__ __launch_bounds__(256) void k_smallmm(
    const double* __restrict__ Ag, const double* __restrict__ Bg,
    const double* __restrict__ Xg, void* __restrict__ Cg,
    int N, long sB, long sC, double alpha, double beta)
{
  const double* A = Ag + (long)blockIdx.z * 65536;
  const double* B = Bg + (long)blockIdx.z * sB;
  const double* Xp = Xg ? (Xg + (long)blockIdx.z * sB) : (const double*)nullptr;
  const int m0 = blockIdx.x * 64, n0 = blockIdx.y * 64;
  const int tid = threadIdx.x;
  __shared__ double As[16][68];
  __shared__ double Bs[16][68];
  const int tx = tid & 15, ty = tid >> 4;
  const int ra = tid >> 2, kqa = (tid & 3) * 4;
  const int kb = tid >> 4, cb = (tid & 15) * 4;
  double acc[4][4] = {};
  for (int k0 = 0; k0 < 256; k0 += 16) {
    const double2* ap = reinterpret_cast<const double2*>(A + (size_t)(m0 + ra) * 256 + k0 + kqa);
    double2 a0 = ap[0], a1 = ap[1];
    As[kqa + 0][ra] = a0.x; As[kqa + 1][ra] = a0.y; As[kqa + 2][ra] = a1.x; As[kqa + 3][ra] = a1.y;
    const double2* bp = reinterpret_cast<const double2*>(B + (size_t)(k0 + kb) * N + n0 + cb);
    double2 b0 = bp[0], b1 = bp[1];
    *reinterpret_cast<double2*>(&Bs[kb][cb]) = b0;
    *reinterpret_cast<double2*>(&Bs[kb][cb + 2]) = b1;
    __syncthreads();
#pragma unroll
    for (int k = 0; k < 16; ++k) {
      double a_[4], b_[4];
#pragma unroll
      for (int i = 0; i < 4; ++i) a_[i] = As[k][ty * 4 + i];
#pragma unroll
      for (int j = 0; j < 4; ++j) b_[j] = Bs[k][tx * 4 + j];
#pragma unroll
      for (int i = 0; i < 4; ++i)
#pragma unroll
        for (int j = 0; j < 4; ++j) acc[i][j] = fma(a_[i], b_[j], acc[i][j]);
    }
    __syncthreads();
  }
#pragma unroll
  for (int i = 0; i < 4; ++i) {
    int row = m0 + ty * 4 + i;
#pragma unroll
    for (int j = 0; j < 4; ++j) {
      int col = n0 + tx * 4 + j;
      double v = alpha * acc[i][j];
      if (beta != 0.0) v = fma(beta, Xp[(size_t)row * N + col], v);
      if constexpr (F32OUT)
        ((float*)Cg)[(long)blockIdx.z * sC + (size_t)row * N + col] = (float)v;
      else
        ((double*)Cg)[(long)blockIdx.z * sC + (size_t)row * N + col] = v;
    }
  }
}

// ---------------- swizzled transpose ---------------------------------------------
// in: (R,C) f32 row-major.  out[k][ 256*(r>>8) + 4*(r&63) + ((r>>6)&3) ] = in[r][k]
__global__ __launch_bounds__(256) void k_swzT(
    const float* __restrict__ in, float* __restrict__ out, int R, int C)
{
  __shared__ float t[32][33];
  const float* ip = in + (size_t)blockIdx.z * R * C;
  float* op = out + (size_t)blockIdx.z * R * C;
  const int r0 = blockIdx.x * 32, c0 = blockIdx.y * 32;
  const int tx = threadIdx.x & 31, ty = threadIdx.x >> 5;
#pragma unroll
  for (int i = 0; i < 4; ++i)
    t[ty + i * 8][tx] = ip[(size_t)(r0 + ty + i * 8) * C + c0 + tx];
  __syncthreads();
#pragma unroll
  for (int i = 0; i < 4; ++i) {
    int k = c0 + ty + i * 8;
    int r = r0 + tx;
    int m = ((r >> 8) << 8) + 4 * (r & 63) + ((r >> 6) & 3);
    op[(size_t)k * R + m] = t[tx][ty + i * 8];
  }
}

// ---------------- persistent ADMM kernel -----------------------------------------
// 512 threads = 8 waves, block = (batch b = bid&7, 8 cols j0). 2 blocks/CU
// (LDS-limited). __launch_bounds__(512,2) -> 128-VGPR cap so e stays in regs.
// Phase 1: each wave: 256 w-rows x 8 cols (R=4/lane), K-chunk 128 -> tree 8>4>2>1.
// Phase 2: wave pairs (w, w+4): 256 g-rows x 8 cols, K split 2 -> pair-reduce.
// s,w in LDS (stride-12 rows); e in VGPRs of waves 0-3. Bitwise == rounds 3/5.
__global__ __launch_bounds__(512, 2) void k_persist2(
    const float* __restrict__ W1s, const float* __restrict__ Vs,
    const float* __restrict__ PVPg, const double* __restrict__ Pg,
    double* __restrict__ Eg)
{
  const int bid = blockIdx.x;
  const int b = bid & 7;
  const int j0 = (bid >> 3) << 3;
  const float* W1p = W1s + (size_t)b * 262144;   // swizzled [1024][256]
  const float* Vp  = Vs  + (size_t)b * 262144;   // swizzled [256][1024]
  const float* Pvp = PVPg + (size_t)b * 262144;  // [256][1024]
  const double* P  = Pg + (size_t)b * 1048576 + j0;
  double* E        = Eg + (size_t)b * 1048576 + j0;

  const int tid = threadIdx.x;
  const int w   = tid >> 6;   // wave 0..7
  const int l   = tid & 63;   // lane

  __shared__ __align__(16) float s_ld[1024 * 12];  // 48 KB, row stride 12
  __shared__ __align__(16) float w_ld[256 * 12];   // 12 KB, row stride 12
  float* RED = s_ld;  // overlay: 4 slots x (64 lanes x 36 floats)

  // zero s
  for (int i = tid; i < 1024 * 12; i += 512) s_ld[i] = 0.0f;

  // e state: wave W<4, lane l owns rows 256*W + 64*t + l (t=0..3), cols 0..7
  double e[4][8];
#pragma unroll
  for (int t = 0; t < 4; ++t)
#pragma unroll
    for (int c = 0; c < 8; ++c) e[t][c] = 0.0;

  const double cg = 2.0 / 1024.0;
  float* slot = RED + (w & 3) * 2304 + l * 36;   // my reduction slot
  __syncthreads();

  for (int it = 0; it < 50; ++it) {
    // ================= phase 1: partial w = W1[:,chunk] @ s[chunk,:] ==========
    float acc[4][8];
#pragma unroll
    for (int t = 0; t < 4; ++t)
#pragma unroll
      for (int c = 0; c < 8; ++c) acc[t][c] = 0.0f;
    {
      const int k0 = w * 128;
      const float* w1ptr = W1p + (size_t)k0 * 256 + 4 * l;
#pragma unroll 4
      for (int k = 0; k < 128; ++k) {
        const float4* srow = reinterpret_cast<const float4*>(&s_ld[(k0 + k) * 12]);
        float4 s0 = srow[0], s1 = srow[1];
        float4 a = *reinterpret_cast<const float4*>(w1ptr + (size_t)k * 256);
        float av[4] = {a.x, a.y, a.z, a.w};
        float sv[8] = {s0.x, s0.y, s0.z, s0.w, s1.x, s1.y, s1.z, s1.w};
#pragma unroll
        for (int t = 0; t < 4; ++t)
#pragma unroll
          for (int c = 0; c < 8; ++c) acc[t][c] = fmaf(av[t], sv[c], acc[t][c]);
      }
    }
    __syncthreads();                       // all p1 sweeps done; s region free

    // reduction tree: ((c0+c4)+(c2+c6)) + ((c1+c5)+(c3+c7)), per chunk-index
    if (w >= 4) {
#pragma unroll
      for (int t = 0; t < 4; ++t)
#pragma unroll
        for (int q = 0; q < 2; ++q) {
          float4 v; v.x = acc[t][q*4]; v.y = acc[t][q*4+1]; v.z = acc[t][q*4+2]; v.w = acc[t][q*4+3];
          *reinterpret_cast<float4*>(slot + t * 8 + q * 4) = v;
        }
    }
    __syncthreads();
    if (w < 4) {
#pragma unroll
      for (int t = 0; t < 4; ++t)
#pragma unroll
        for (int q = 0; q < 2; ++q) {
          float4 v = *reinterpret_cast<const float4*>(slot + t * 8 + q * 4);
          acc[t][q*4] += v.x; acc[t][q*4+1] += v.y; acc[t][q*4+2] += v.z; acc[t][q*4+3] += v.w;
        }
    }
    __syncthreads();
    if (w == 2 || w == 3) {
      float* s2p = RED + (w - 2) * 2304 + l * 36;
#pragma unroll
      for (int t = 0; t < 4; ++t)
#pragma unroll
        for (int q = 0; q < 2; ++q) {
          float4 v; v.x = acc[t][q*4]; v.y = acc[t][q*4+1]; v.z = acc[t][q*4+2]; v.w = acc[t][q*4+3];
          *reinterpret_cast<float4*>(s2p + t * 8 + q * 4) = v;
        }
    }
    __syncthreads();
    if (w < 2) {
#pragma unroll
      for (int t = 0; t < 4; ++t)
#pragma unroll
        for (int q = 0; q < 2; ++q) {
          float4 v = *reinterpret_cast<const float4*>(slot + t * 8 + q * 4);
          acc[t][q*4] += v.x; acc[t][q*4+1] += v.y; acc[t][q*4+2] += v.z; acc[t][q*4+3] += v.w;
        }
    }
    __syncthreads();
    if (w == 1) {
      float* s0p = RED + l * 36;
#pragma unroll
      for (int t = 0; t < 4; ++t)
#pragma unroll
        for (int q = 0; q < 2; ++q) {
          float4 v; v.x = acc[t][q*4]; v.y = acc[t][q*4+1]; v.z = acc[t][q*4+2]; v.w = acc[t][q*4+3];
          *reinterpret_cast<float4*>(s0p + t * 8 + q * 4) = v;
        }
    }
    __syncthreads();
    if (w == 0) {
#pragma unroll
      for (int t = 0; t < 4; ++t) {
        const int row = l + 64 * t;
        const float* pvrow = Pvp + (size_t)row * 1024 + j0;
        float* wrow = &w_ld[row * 12];
#pragma unroll
        for (int q = 0; q < 2; ++q) {
          float4 v = *reinterpret_cast<const float4*>(slot + t * 8 + q * 4);
          float4 pv = *reinterpret_cast<const float4*>(pvrow + q * 4);
          float4 o;
          o.x = acc[t][q*4]   + v.x - pv.x;
          o.y = acc[t][q*4+1] + v.y - pv.y;
          o.z = acc[t][q*4+2] + v.z - pv.z;
          o.w = acc[t][q*4+3] + v.w - pv.w;
          *reinterpret_cast<float4*>(wrow + q * 4) = o;
        }
      }
    }
    __syncthreads();                       // w_ld ready

    // ================= phase 2: g = V @ w, rows 256*(w&3).., K split 2 ========
    float g[4][8];
#pragma unroll
    for (int t = 0; t < 4; ++t)
#pragma unroll
      for (int c = 0; c < 8; ++c) g[t][c] = 0.0f;
    {
      const int G = w & 3;
      const int kb = (w >> 2) * 128;
      const float* vptr = Vp + (size_t)kb * 1024 + 256 * G + 4 * l;
#pragma unroll 4
      for (int k = 0; k < 128; ++k) {
        const float4* wrow = reinterpret_cast<const float4*>(&w_ld[(kb + k) * 12]);
        float4 q0 = wrow[0], q1 = wrow[1];
        float4 a = *reinterpret_cast<const float4*>(vptr + (size_t)k * 1024);
        float av[4] = {a.x, a.y, a.z, a.w};
        float wv[8] = {q0.x, q0.y, q0.z, q0.w, q1.x, q1.y, q1.z, q1.w};
#pragma unroll
        for (int t = 0; t < 4; ++t)
#pragma unroll
          for (int c = 0; c < 8; ++c) g[t][c] = fmaf(av[t], wv[c], g[t][c]);
      }
    }
    if (w >= 4) {
#pragma unroll
      for (int t = 0; t < 4; ++t)
#pragma unroll
        for (int q = 0; q < 2; ++q) {
          float4 v; v.x = g[t][q*4]; v.y = g[t][q*4+1]; v.z = g[t][q*4+2]; v.w = g[t][q*4+3];
          *reinterpret_cast<float4*>(slot + t * 8 + q * 4) = v;
        }
    }
    __syncthreads();
    if (w < 4) {
#pragma unroll
      for (int t = 0; t < 4; ++t)
#pragma unroll
        for (int q = 0; q < 2; ++q) {
          float4 v = *reinterpret_cast<const float4*>(slot + t * 8 + q * 4);
          g[t][q*4] += v.x; g[t][q*4+1] += v.y; g[t][q*4+2] += v.z; g[t][q*4+3] += v.w;
        }
    }
    __syncthreads();                       // RED reads done; s region writable

    // ================= elementwise (waves 0-3) ================================
    if (w < 4) {
#pragma unroll
      for (int t = 0; t < 4; ++t) {
        const int row = 256 * w + 64 * t + l;
        const double* prow = P + (size_t)row * 1024;
        double p_[8];
#pragma unroll
        for (int q = 0; q < 4; ++q) {
          double2 pv = *reinterpret_cast<const double2*>(prow + 2 * q);
          p_[2*q] = pv.x; p_[2*q+1] = pv.y;
        }
        float s_[8];
#pragma unroll
        for (int c = 0; c < 8; ++c) {
          double z = clip01(e[t][c]);
          double en = z - p_[c] - cg * (double)g[t][c];
          e[t][c] = en;
          s_[c] = (float)(2.0 * clip01(en) - en);
        }
        float* srow = &s_ld[row * 12];
#pragma unroll
        for (int q = 0; q < 2; ++q) {
          float4 v; v.x = s_[q*4]; v.y = s_[q*4+1]; v.z = s_[q*4+2]; v.w = s_[q*4+3];
          *reinterpret_cast<float4*>(srow + q * 4) = v;
        }
      }
    }
    __syncthreads();                       // s ready for next iter
  }

  // final E store (waves 0-3)
  if (w < 4) {
#pragma unroll
    for (int t = 0; t < 4; ++t) {
      const int row = 256 * w + 64 * t + l;
      double* erow = E + (size_t)row * 1024;
#pragma unroll
      for (int q = 0; q < 4; ++q) {
        double2 v; v.x = e[t][2*q]; v.y = e[t][2*q+1];
        *reinterpret_cast<double2*>(erow + 2 * q) = v;
      }
    }
  }
}

// ---------------- per-(b,n) count -> inverse scale ------------------------------
__global__ __launch_bounds__(256) void k_count(const double* __restrict__ Eg, float* __restrict__ inv)
{
  const int bz = blockIdx.y;
  const int j = blockIdx.x * 256 + threadIdx.x;
  const double* E = Eg + (size_t)bz * 1048576;
  int c = 0;
  for (int i = 0; i < 1024; ++i) c += (E[(size_t)i * 1024 + j] > 0.5) ? 1 : 0;
  inv[bz * 1024 + j] = (float)(1.0 / (((double)c) + 1e-10) / 1024.0);
}

// ---------------- output masked GEMM: out[j,dd] = inv[j] * sum_i mask(e) V[i,dd] --
__global__ __launch_bounds__(256) void k_out(
    const double* __restrict__ Eg, const float* __restrict__ Vg,
    const float* __restrict__ invg, float* __restrict__ Og)
{
  const double* E = Eg + (size_t)blockIdx.z * 1048576;
  const float* Vv = Vg + (size_t)blockIdx.z * 262144;
  const float* inv = invg + blockIdx.z * 1024;
  float* O = Og + (size_t)blockIdx.z * 262144;
  const int j0 = blockIdx.x * 64, d0 = blockIdx.y * 128;
  const int tid = threadIdx.x;
  __shared__ float As[32][68];
  __shared__ float Bs[32][132];
  const int tx = tid & 15, ty = tid >> 4;
  const int ka = tid >> 3, ja = (tid & 7) * 8;
  const int rb = tid >> 5, cb = (tid & 31) * 4;
  float acc[4][8] = {};
  for (int k0 = 0; k0 < 1024; k0 += 32) {
    {
      const double2* ep = reinterpret_cast<const double2*>(E + (size_t)(k0 + ka) * 1024 + j0 + ja);
      double2 e0 = ep[0], e1 = ep[1], e2 = ep[2], e3 = ep[3];
      As[ka][ja + 0] = (e0.x > 0.5) ? 1.0f : 0.0f;
      As[ka][ja + 1] = (e0.y > 0.5) ? 1.0f : 0.0f;
      As[ka][ja + 2] = (e1.x > 0.5) ? 1.0f : 0.0f;
      As[ka][ja + 3] = (e1.y > 0.5) ? 1.0f : 0.0f;
      As[ka][ja + 4] = (e2.x > 0.5) ? 1.0f : 0.0f;
      As[ka][ja + 5] = (e2.y > 0.5) ? 1.0f : 0.0f;
      As[ka][ja + 6] = (e3.x > 0.5) ? 1.0f : 0.0f;
      As[ka][ja + 7] = (e3.y > 0.5) ? 1.0f : 0.0f;
    }
#pragma unroll
    for (int p = 0; p < 4; ++p) {
      int krow = rb + p * 8;
      float4 bv = *reinterpret_cast<const float4*>(Vv + (size_t)(k0 + krow) * 256 + d0 + cb);
      *reinterpret_cast<float4*>(&Bs[krow][cb]) = bv;
    }
    __syncthreads();
#pragma unroll
    for (int kk = 0; kk < 32; ++kk) {
      float4 av = *reinterpret_cast<const float4*>(&As[kk][ty * 4]);
      float4 b0 = *reinterpret_cast<const float4*>(&Bs[kk][tx * 8]);
      float4 b1 = *reinterpret_cast<const float4*>(&Bs[kk][tx * 8 + 4]);
      float a_[4] = {av.x, av.y, av.z, av.w};
      float b_[8] = {b0.x, b0.y, b0.z, b0.w, b1.x, b1.y, b1.z, b1.w};
#pragma unroll
      for (int i = 0; i < 4; ++i)
#pragma unroll
        for (int j = 0; j < 8; ++j) acc[i][j] = fmaf(a_[i], b_[j], acc[i][j]);
    }
    __syncthreads();
  }
#pragma unroll
  for (int i = 0; i < 4; ++i) {
    int row = j0 + ty * 4 + i;
    float sc = inv[row];
    size_t base = (size_t)row * 256 + d0 + tx * 8;
    float4 o0 = {acc[i][0] * sc, acc[i][1] * sc, acc[i][2] * sc, acc[i][3] * sc};
    float4 o1 = {acc[i][4] * sc, acc[i][5] * sc, acc[i][6] * sc, acc[i][7] * sc};
    *reinterpret_cast<float4*>(O + base) = o0;
    *reinterpret_cast<float4*>(O + base + 4) = o1;
  }
}

extern "C" void kernel_launch(void* const* d_in, const int* in_sizes, int n_in,
                              void* d_out, int out_size, void* d_ws, size_t ws_size,
                              hipStream_t stream)
{
  const float* Q = (const float*)d_in[0];   // (8,1024,256)
  const float* V = (const float*)d_in[1];   // (8,1024,256)
  float* out = (float*)d_out;               // (8,1024,256)
  char* ws = (char*)d_ws;

  // workspace layout (bytes) — total ~193 MB
  const size_t OFF_E   = 0;                  // e final, f64 (8,1024,1024)
  const size_t OFF_P   = 67108864;           // P, f64 (8,1024,1024)
  const size_t SCR     = 134217728;          // scratch region
  const size_t OFF_G   = SCR;
  const size_t OFF_AD  = SCR + 4194304;
  const size_t OFF_X   = SCR + 8388608;
  const size_t OFF_Y   = SCR + 12582912;
  const size_t OFF_X2  = SCR + 16777216;     // final M
  const size_t OFF_PV64= SCR;                // f64 (8,256,1024) overlays G..Y
  const size_t OFF_W1Z = SCR;                // fp32 swizzled W1 (8MB) — after PV64 dead
  const size_t OFF_VZ  = SCR + 8388608;      // fp32 swizzled V (8MB)
  const size_t OFF_W1  = 176160768;          // fp32 W1 (8,256,1024)
  const size_t OFF_PVP = 184549376;          // fp32 Pvp (8,256,1024)
  const size_t OFF_INV = 192937984;          // fp32 (8,1024)

  double* E    = (double*)(ws + OFF_E);
  double* P    = (double*)(ws + OFF_P);
  double* G    = (double*)(ws + OFF_G);
  double* Ad   = (double*)(ws + OFF_AD);
  double* X    = (double*)(ws + OFF_X);
  double* Y    = (double*)(ws + OFF_Y);
  double* X2   = (double*)(ws + OFF_X2);
  double* PV64 = (double*)(ws + OFF_PV64);
  float*  W1Z  = (float*)(ws + OFF_W1Z);
  float*  VZ   = (float*)(ws + OFF_VZ);
  float*  W1   = (float*)(ws + OFF_W1);
  float*  PVP  = (float*)(ws + OFF_PVP);
  float*  INV  = (float*)(ws + OFF_INV);

  (void)in_sizes; (void)n_in; (void)out_size; (void)ws_size;

  // P = (-2/1024) * V @ Q^T + 0.1/1024     (f64, K=256)
  k_gemm_nt<float, double><<<dim3(16, 16, 8), 256, 0, stream>>>(
      V, Q, P, 1024, 1024, 256, 262144, 262144, 1048576, -2.0 / 1024.0, 0.1 / 1024.0);

  // G = (1/1024^2) V^T @ V   (f64, 256x256)
  k_gemm_tn<float><<<dim3(4, 4, 8), 256, 0, stream>>>(
      V, V, G, 256, 256, 1024, 262144, 262144, 65536, 1.0 / 1048576.0);

  // Ad = I + 2G, X0 = I - 2G
  k_adx0<<<dim3(2048), 256, 0, stream>>>(G, Ad, X);

  // Newton-Schulz x3: X <- X(2I - Ad X); final M in X2
  for (int it = 0; it < 3; ++it) {
    const double* Xc = (it % 2 == 0) ? X : X2;
    double* Xn = (it % 2 == 0) ? X2 : X;
    k_smallmm<false><<<dim3(4, 4, 8), 256, 0, stream>>>(
        Ad, Xc, (const double*)nullptr, (void*)Y, 256, 65536, 65536, 1.0, 0.0);
    k_smallmm<false><<<dim3(4, 4, 8), 256, 0, stream>>>(
        Xc, Y, Xc, (void*)Xn, 256, 65536, 65536, -1.0, 2.0);
  }

  // PV64 = (1/1024) V^T @ P   (f64, 256x1024)
  k_gemm_tn<double><<<dim3(4, 16, 8), 256, 0, stream>>>(
      V, P, PV64, 256, 1024, 1024, 262144, 1048576, 262144, 1.0 / 1024.0);

  // PVP = M @ PV64  (fp32 out)
  k_smallmm<true><<<dim3(4, 16, 8), 256, 0, stream>>>(
      X2, PV64, (const double*)nullptr, (void*)PVP, 1024, 262144, 262144, 1.0, 0.0);

  // W1 = (1/1024) M @ V^T  (fp32 out, 256x1024)
  k_gemm_nt<double, float><<<dim3(4, 16, 8), 256, 0, stream>>>(
      X2, V, W1, 256, 1024, 256, 65536, 262144, 262144, 1.0 / 1024.0, 0.0);

  // swizzled operand layouts (PV64/X2 dead now)
  k_swzT<<<dim3(8, 32, 8), 256, 0, stream>>>(W1, W1Z, 256, 1024);
  k_swzT<<<dim3(32, 8, 8), 256, 0, stream>>>(V, VZ, 1024, 256);

  // 50 ADMM iterations, persistent: 1024 blocks x 512 threads (2 blocks/CU)
  k_persist2<<<dim3(1024), 512, 0, stream>>>(W1Z, VZ, PVP, P, E);

  // epilogue
  k_count<<<dim3(4, 8), 256, 0, stream>>>(E, INV);
  k_out<<<dim3(16, 2, 8), 256, 0, stream>>>(E, V, INV, out);
}

// Round 7
// 10454.694 us; speedup vs baseline: 1.5378x; 1.5378x over previous
//
#include <hip/hip_runtime.h>

// Problem constants (b=8, n=1024, m=1024, d=256, RHO=1, LAMBDA=0.1, 50 iters)
// ADMM box-QP via Woodbury on A = I + 2 Vs Vs^T  (Vs = V / 1024).
//   state e (f64) in global E:  z = clip(e), s = 2z - e   (s derived from E on the fly)
//   w  = W1 @ s - Pvp          (fp32, K=1024, K-split 4 -> partials)
//   e' = clip(e) - P - (2/1024) * (V @ w)   (fp32 K=256 GEMM + f64 elementwise)
// Non-fused: 2 dispatches/iter, both at 4 blocks/CU (16 waves/CU).

__device__ __forceinline__ double clip01(double v) { return fmin(fmax(v, 0.0), 1.0); }

// ---------------- NT GEMM, f64 accumulate: C = (TC)(alpha * A@B^T + c0) ----------
template <typename TA, typename TC>
__global__ __launch_bounds__(256) void k_gemm_nt(
    const TA* __restrict__ Ag, const float* __restrict__ Bg, TC* __restrict__ Cg,
    int M, int N, int K, long sA, long sB, long sC, double alpha, double c0)
{
  const TA* A = Ag + (long)blockIdx.z * sA;
  const float* B = Bg + (long)blockIdx.z * sB;
  TC* C = Cg + (long)blockIdx.z * sC;
  const int m0 = blockIdx.x * 64, n0 = blockIdx.y * 64;
  const int tid = threadIdx.x;
  __shared__ double As[32][68];
  __shared__ double Bs[32][68];
  const int tx = tid & 15, ty = tid >> 4;
  const int r = tid >> 2, kq = (tid & 3) * 8;
  double acc[4][4] = {};
  for (int k0 = 0; k0 < K; k0 += 32) {
    if constexpr (sizeof(TA) == 4) {
      const float4* ap = reinterpret_cast<const float4*>(A + (size_t)(m0 + r) * K + k0 + kq);
      float4 a0 = ap[0], a1 = ap[1];
      As[kq+0][r] = a0.x; As[kq+1][r] = a0.y; As[kq+2][r] = a0.z; As[kq+3][r] = a0.w;
      As[kq+4][r] = a1.x; As[kq+5][r] = a1.y; As[kq+6][r] = a1.z; As[kq+7][r] = a1.w;
    } else {
      const double2* ap = reinterpret_cast<const double2*>(A + (size_t)(m0 + r) * K + k0 + kq);
      double2 a0 = ap[0], a1 = ap[1], a2 = ap[2], a3 = ap[3];
      As[kq+0][r] = a0.x; As[kq+1][r] = a0.y; As[kq+2][r] = a1.x; As[kq+3][r] = a1.y;
      As[kq+4][r] = a2.x; As[kq+5][r] = a2.y; As[kq+6][r] = a3.x; As[kq+7][r] = a3.y;
    }
    {
      const float4* bp = reinterpret_cast<const float4*>(B + (size_t)(n0 + r) * K + k0 + kq);
      float4 b0 = bp[0], b1 = bp[1];
      Bs[kq+0][r] = b0.x; Bs[kq+1][r] = b0.y; Bs[kq+2][r] = b0.z; Bs[kq+3][r] = b0.w;
      Bs[kq+4][r] = b1.x; Bs[kq+5][r] = b1.y; Bs[kq+6][r] = b1.z; Bs[kq+7][r] = b1.w;
    }
    __syncthreads();
#pragma unroll
    for (int kk = 0; kk < 32; ++kk) {
      double a_[4], b_[4];
#pragma unroll
      for (int i = 0; i < 4; ++i) a_[i] = As[kk][ty * 4 + i];
#pragma unroll
      for (int j = 0; j < 4; ++j) b_[j] = Bs[kk][tx * 4 + j];
#pragma unroll
      for (int i = 0; i < 4; ++i)
#pragma unroll
        for (int j = 0; j < 4; ++j) acc[i][j] = fma(a_[i], b_[j], acc[i][j]);
    }
    __syncthreads();
  }
#pragma unroll
  for (int i = 0; i < 4; ++i) {
    int row = m0 + ty * 4 + i;
#pragma unroll
    for (int j = 0; j < 4; ++j)
      C[(size_t)row * N + n0 + tx * 4 + j] = (TC)(alpha * acc[i][j] + c0);
  }
}

// ---------------- TN GEMM, f64 accumulate: C[MxN] = scale * A^T @ B -------------
template <typename TB>
__global__ __launch_bounds__(256) void k_gemm_tn(
    const float* __restrict__ Ag, const TB* __restrict__ Bg, double* __restrict__ Cg,
    int M, int N, int K, long sA, long sB, long sC, double scale)
{
  const float* A = Ag + (long)blockIdx.z * sA;
  const TB* B = Bg + (long)blockIdx.z * sB;
  double* C = Cg + (long)blockIdx.z * sC;
  const int m0 = blockIdx.x * 64, n0 = blockIdx.y * 64;
  const int tid = threadIdx.x;
  __shared__ float As[16][68];
  __shared__ double Bs[16][68];
  const int tx = tid & 15, ty = tid >> 4;
  const int kk = tid >> 4, c4 = (tid & 15) * 4;
  double acc[4][4] = {};
  for (int k0 = 0; k0 < K; k0 += 16) {
    float4 av = *reinterpret_cast<const float4*>(A + (size_t)(k0 + kk) * M + m0 + c4);
    *reinterpret_cast<float4*>(&As[kk][c4]) = av;
    if constexpr (sizeof(TB) == 4) {
      float4 bv = *reinterpret_cast<const float4*>(B + (size_t)(k0 + kk) * N + n0 + c4);
      Bs[kk][c4 + 0] = bv.x; Bs[kk][c4 + 1] = bv.y; Bs[kk][c4 + 2] = bv.z; Bs[kk][c4 + 3] = bv.w;
    } else {
      const double2* bp = reinterpret_cast<const double2*>(B + (size_t)(k0 + kk) * N + n0 + c4);
      double2 b0 = bp[0], b1 = bp[1];
      *reinterpret_cast<double2*>(&Bs[kk][c4]) = b0;
      *reinterpret_cast<double2*>(&Bs[kk][c4 + 2]) = b1;
    }
    __syncthreads();
#pragma unroll
    for (int k = 0; k < 16; ++k) {
      double a_[4], b_[4];
#pragma unroll
      for (int i = 0; i < 4; ++i) a_[i] = (double)As[k][ty * 4 + i];
#pragma unroll
      for (int j = 0; j < 4; ++j) b_[j] = Bs[k][tx * 4 + j];
#pragma unroll
      for (int i = 0; i < 4; ++i)
#pragma unroll
        for (int j = 0; j < 4; ++j) acc[i][j] = fma(a_[i], b_[j], acc[i][j]);
    }
    __syncthreads();
  }
#pragma unroll
  for (int i = 0; i < 4; ++i) {
    int row = m0 + ty * 4 + i;
#pragma unroll
    for (int j = 0; j < 4; ++j)
      C[(size_t)row * N + n0 + tx * 4 + j] = scale * acc[i][j];
  }
}

// ---------------- Ad = I + 2G, X0 = I - 2G --------------------------------------
__global__ __launch_bounds__(256) void k_adx0(const double* __restrict__ G,
                                              double* __restrict__ Ad, double* __restrict__ X)
{
  size_t idx = (size_t)blockIdx.x * 256 + threadIdx.x;
  double g = G[idx];
  int ij = (int)(idx & 65535);
  double dg = ((ij >> 8) == (ij & 255)) ? 1.0 : 0.0;
  Ad[idx] = dg + 2.0 * g;
  X[idx] = dg - 2.0 * g;
}

// ---------------- small f64 NN GEMM: C = alpha*A@B + beta*Xin -------------------
template <bool F32OUT>
__global__ __launch_bounds__(256) void k_smallmm(
    const double* __restrict__ Ag, const double* __restrict__ Bg,
    const double* __restrict__ Xg, void* __restrict__ Cg,
    int N, long sB, long sC, double alpha, double beta)
{
  const double* A = Ag + (long)blockIdx.z * 65536;
  const double* B = Bg + (long)blockIdx.z * sB;
  const double* Xp = Xg ? (Xg + (long)blockIdx.z * sB) : (const double*)nullptr;
  const int m0 = blockIdx.x * 64, n0 = blockIdx.y * 64;
  const int tid = threadIdx.x;
  __shared__ double As[16][68];
  __shared__ double Bs[16][68];
  const int tx = tid & 15, ty = tid >> 4;
  const int ra = tid >> 2, kqa = (tid & 3) * 4;
  const int kb = tid >> 4, cb = (tid & 15) * 4;
  double acc[4][4] = {};
  for (int k0 = 0; k0 < 256; k0 += 16) {
    const double2* ap = reinterpret_cast<const double2*>(A + (size_t)(m0 + ra) * 256 + k0 + kqa);
    double2 a0 = ap[0], a1 = ap[1];
    As[kqa + 0][ra] = a0.x; As[kqa + 1][ra] = a0.y; As[kqa + 2][ra] = a1.x; As[kqa + 3][ra] = a1.y;
    const double2* bp = reinterpret_cast<const double2*>(B + (size_t)(k0 + kb) * N + n0 + cb);
    double2 b0 = bp[0], b1 = bp[1];
    *reinterpret_cast<double2*>(&Bs[kb][cb]) = b0;
    *reinterpret_cast<double2*>(&Bs[kb][cb + 2]) = b1;
    __syncthreads();
#pragma unroll
    for (int k = 0; k < 16; ++k) {
      double a_[4], b_[4];
#pragma unroll
      for (int i = 0; i < 4; ++i) a_[i] = As[k][ty * 4 + i];
#pragma unroll
      for (int j = 0; j < 4; ++j) b_[j] = Bs[k][tx * 4 + j];
#pragma unroll
      for (int i = 0; i < 4; ++i)
#pragma unroll
        for (int j = 0; j < 4; ++j) acc[i][j] = fma(a_[i], b_[j], acc[i][j]);
    }
    __syncthreads();
  }
#pragma unroll
  for (int i = 0; i < 4; ++i) {
    int row = m0 + ty * 4 + i;
#pragma unroll
    for (int j = 0; j < 4; ++j) {
      int col = n0 + tx * 4 + j;
      double v = alpha * acc[i][j];
      if (beta != 0.0) v = fma(beta, Xp[(size_t)row * N + col], v);
      if constexpr (F32OUT)
        ((float*)Cg)[(long)blockIdx.z * sC + (size_t)row * N + col] = (float)v;
      else
        ((double*)Cg)[(long)blockIdx.z * sC + (size_t)row * N + col] = v;
    }
  }
}

// ---------------- iter GEMM A: w_part[kc] = W1[:,kc-chunk] @ s[kc-chunk,:] -------
// s derived on the fly from E: s = (float)(2*clip(e) - e)  (bitwise == stored s)
// BM=64, BN=128, BK=32, K-chunk=256, micro 4x8. grid (4,8,32) z=batch*4+kc.
__global__ __launch_bounds__(256) void k_iterA3(
    const float* __restrict__ W1g, const double* __restrict__ Eg,
    float* __restrict__ WPg)
{
  const int z = blockIdx.z;
  const int b = z >> 2, kc = z & 3;
  const float* A = W1g + (size_t)b * 262144;        // [256][1024]
  const double* Ee = Eg + (size_t)b * 1048576;      // [1024][1024]
  float* C = WPg + ((size_t)kc * 8 + b) * 262144;   // [4][8][256][1024]
  const int m0 = blockIdx.x * 64, n0 = blockIdx.y * 128;
  const int kbase = kc * 256;
  const int tid = threadIdx.x;
  __shared__ __align__(16) float As[32][68];
  __shared__ __align__(16) float Bs[32][132];
  const int tx = tid & 15, ty = tid >> 4;
  const int ra = tid >> 3, qa = tid & 7;         // A stage
  const int kb = tid >> 3, cb = (tid & 7) * 16;  // B stage
  float acc[4][8] = {};
  for (int t = 0; t < 8; ++t) {
    const int k0 = kbase + t * 32;
    // stage A (W1, transposed into As[k][m])
    {
      float4 a0 = *reinterpret_cast<const float4*>(A + (size_t)(m0 + ra) * 1024 + k0 + qa * 4);
      float4 a1 = *reinterpret_cast<const float4*>(A + (size_t)(m0 + ra + 32) * 1024 + k0 + qa * 4);
      As[qa*4+0][ra] = a0.x; As[qa*4+1][ra] = a0.y; As[qa*4+2][ra] = a0.z; As[qa*4+3][ra] = a0.w;
      As[qa*4+0][ra+32] = a1.x; As[qa*4+1][ra+32] = a1.y; As[qa*4+2][ra+32] = a1.z; As[qa*4+3][ra+32] = a1.w;
    }
    // stage B: read E row, convert to s
    {
      const double* erow = Ee + (size_t)(k0 + kb) * 1024 + n0 + cb;
      float sv[16];
#pragma unroll
      for (int q = 0; q < 8; ++q) {
        double2 ev = *reinterpret_cast<const double2*>(erow + 2 * q);
        double z0 = clip01(ev.x), z1 = clip01(ev.y);
        sv[2*q]   = (float)(2.0 * z0 - ev.x);
        sv[2*q+1] = (float)(2.0 * z1 - ev.y);
      }
#pragma unroll
      for (int q = 0; q < 4; ++q) {
        float4 v; v.x = sv[q*4]; v.y = sv[q*4+1]; v.z = sv[q*4+2]; v.w = sv[q*4+3];
        *reinterpret_cast<float4*>(&Bs[kb][cb + q * 4]) = v;
      }
    }
    __syncthreads();
#pragma unroll
    for (int k = 0; k < 32; ++k) {
      float4 av = *reinterpret_cast<const float4*>(&As[k][ty * 4]);
      float4 b0 = *reinterpret_cast<const float4*>(&Bs[k][tx * 8]);
      float4 b1 = *reinterpret_cast<const float4*>(&Bs[k][tx * 8 + 4]);
      float a_[4] = {av.x, av.y, av.z, av.w};
      float b_[8] = {b0.x, b0.y, b0.z, b0.w, b1.x, b1.y, b1.z, b1.w};
#pragma unroll
      for (int i = 0; i < 4; ++i)
#pragma unroll
        for (int j = 0; j < 8; ++j) acc[i][j] = fmaf(a_[i], b_[j], acc[i][j]);
    }
    __syncthreads();
  }
#pragma unroll
  for (int i = 0; i < 4; ++i) {
    size_t base = (size_t)(m0 + ty * 4 + i) * 1024 + n0 + tx * 8;
    float4 o0; o0.x = acc[i][0]; o0.y = acc[i][1]; o0.z = acc[i][2]; o0.w = acc[i][3];
    float4 o1; o1.x = acc[i][4]; o1.y = acc[i][5]; o1.z = acc[i][6]; o1.w = acc[i][7];
    *reinterpret_cast<float4*>(C + base) = o0;
    *reinterpret_cast<float4*>(C + base + 4) = o1;
  }
}

// ---------------- iter GEMM C + elementwise --------------------------------------
// B-stage: w = ((p0+p1)+p2)+p3 - Pvp;  g = V @ w;  e' = clip(e) - P - cg*g (f64).
// BM=64, BN=128, BK=32, K=256, micro 4x8. grid (16,8,8).
__global__ __launch_bounds__(256) void k_iterC3(
    const float* __restrict__ Vg, const float* __restrict__ WPg,
    const float* __restrict__ PVPg, const double* __restrict__ Pg,
    double* __restrict__ Eg)
{
  const int b = blockIdx.z;
  const float* A = Vg + (size_t)b * 262144;         // [1024][256]
  const float* Pvp = PVPg + (size_t)b * 262144;     // [256][1024]
  const double* P = Pg + (size_t)b * 1048576;       // [1024][1024]
  double* E = Eg + (size_t)b * 1048576;
  const int m0 = blockIdx.x * 64, n0 = blockIdx.y * 128;
  const int tid = threadIdx.x;
  __shared__ __align__(16) float As[32][68];
  __shared__ __align__(16) float Bs[32][132];
  const int tx = tid & 15, ty = tid >> 4;
  const int ra = tid >> 3, qa = tid & 7;
  const int kb = tid >> 3, cb = (tid & 7) * 16;
  float acc[4][8] = {};
  for (int t = 0; t < 8; ++t) {
    const int k0 = t * 32;
    // stage A (V, transposed into As[k][m])
    {
      float4 a0 = *reinterpret_cast<const float4*>(A + (size_t)(m0 + ra) * 256 + k0 + qa * 4);
      float4 a1 = *reinterpret_cast<const float4*>(A + (size_t)(m0 + ra + 32) * 256 + k0 + qa * 4);
      As[qa*4+0][ra] = a0.x; As[qa*4+1][ra] = a0.y; As[qa*4+2][ra] = a0.z; As[qa*4+3][ra] = a0.w;
      As[qa*4+0][ra+32] = a1.x; As[qa*4+1][ra+32] = a1.y; As[qa*4+2][ra+32] = a1.z; As[qa*4+3][ra+32] = a1.w;
    }
    // stage B: sum 4 partials, subtract Pvp
    {
      size_t off = (size_t)(k0 + kb) * 1024 + n0 + cb;
#pragma unroll
      for (int q = 0; q < 4; ++q) {
        float4 p0 = *reinterpret_cast<const float4*>(WPg + ((size_t)0 * 8 + b) * 262144 + off + q * 4);
        float4 p1 = *reinterpret_cast<const float4*>(WPg + ((size_t)1 * 8 + b) * 262144 + off + q * 4);
        float4 p2 = *reinterpret_cast<const float4*>(WPg + ((size_t)2 * 8 + b) * 262144 + off + q * 4);
        float4 p3 = *reinterpret_cast<const float4*>(WPg + ((size_t)3 * 8 + b) * 262144 + off + q * 4);
        float4 pv = *reinterpret_cast<const float4*>(Pvp + off + q * 4);
        float4 v;
        v.x = ((p0.x + p1.x) + p2.x) + p3.x - pv.x;
        v.y = ((p0.y + p1.y) + p2.y) + p3.y - pv.y;
        v.z = ((p0.z + p1.z) + p2.z) + p3.z - pv.z;
        v.w = ((p0.w + p1.w) + p2.w) + p3.w - pv.w;
        *reinterpret_cast<float4*>(&Bs[kb][cb + q * 4]) = v;
      }
    }
    __syncthreads();
#pragma unroll
    for (int k = 0; k < 32; ++k) {
      float4 av = *reinterpret_cast<const float4*>(&As[k][ty * 4]);
      float4 b0 = *reinterpret_cast<const float4*>(&Bs[k][tx * 8]);
      float4 b1 = *reinterpret_cast<const float4*>(&Bs[k][tx * 8 + 4]);
      float a_[4] = {av.x, av.y, av.z, av.w};
      float b_[8] = {b0.x, b0.y, b0.z, b0.w, b1.x, b1.y, b1.z, b1.w};
#pragma unroll
      for (int i = 0; i < 4; ++i)
#pragma unroll
        for (int j = 0; j < 8; ++j) acc[i][j] = fmaf(a_[i], b_[j], acc[i][j]);
    }
    __syncthreads();
  }
  // elementwise epilogue: e' = clip(e) - P - cg*g, write E
  const double cg = 2.0 / 1024.0;
#pragma unroll
  for (int i = 0; i < 4; ++i) {
    size_t base = (size_t)(m0 + ty * 4 + i) * 1024 + n0 + tx * 8;
    double e_[8], p_[8];
#pragma unroll
    for (int q = 0; q < 4; ++q) {
      double2 ev = *reinterpret_cast<const double2*>(E + base + 2 * q);
      double2 pv = *reinterpret_cast<const double2*>(P + base + 2 * q);
      e_[2*q] = ev.x; e_[2*q+1] = ev.y;
      p_[2*q] = pv.x; p_[2*q+1] = pv.y;
    }
#pragma unroll
    for (int j = 0; j < 8; ++j) {
      double zz = clip01(e_[j]);
      e_[j] = zz - p_[j] - cg * (double)acc[i][j];
    }
#pragma unroll
    for (int q = 0; q < 4; ++q) {
      double2 ev; ev.x = e_[2*q]; ev.y = e_[2*q+1];
      *reinterpret_cast<double2*>(E + base + 2 * q) = ev;
    }
  }
}

// ---------------- per-(b,n) count -> inverse scale ------------------------------
__global__ __launch_bounds__(256) void k_count(const double* __restrict__ Eg, float* __restrict__ inv)
{
  const int bz = blockIdx.y;
  const int j = blockIdx.x * 256 + threadIdx.x;
  const double* E = Eg + (size_t)bz * 1048576;
  int c = 0;
  for (int i = 0; i < 1024; ++i) c += (E[(size_t)i * 1024 + j] > 0.5) ? 1 : 0;
  inv[bz * 1024 + j] = (float)(1.0 / (((double)c) + 1e-10) / 1024.0);
}

// ---------------- output masked GEMM: out[j,dd] = inv[j] * sum_i mask(e) V[i,dd] --
__global__ __launch_bounds__(256) void k_out(
    const double* __restrict__ Eg, const float* __restrict__ Vg,
    const float* __restrict__ invg, float* __restrict__ Og)
{
  const double* E = Eg + (size_t)blockIdx.z * 1048576;
  const float* Vv = Vg + (size_t)blockIdx.z * 262144;
  const float* inv = invg + blockIdx.z * 1024;
  float* O = Og + (size_t)blockIdx.z * 262144;
  const int j0 = blockIdx.x * 64, d0 = blockIdx.y * 128;
  const int tid = threadIdx.x;
  __shared__ float As[32][68];
  __shared__ float Bs[32][132];
  const int tx = tid & 15, ty = tid >> 4;
  const int ka = tid >> 3, ja = (tid & 7) * 8;
  const int rb = tid >> 5, cbo = (tid & 31) * 4;
  float acc[4][8] = {};
  for (int k0 = 0; k0 < 1024; k0 += 32) {
    {
      const double2* ep = reinterpret_cast<const double2*>(E + (size_t)(k0 + ka) * 1024 + j0 + ja);
      double2 e0 = ep[0], e1 = ep[1], e2 = ep[2], e3 = ep[3];
      As[ka][ja + 0] = (e0.x > 0.5) ? 1.0f : 0.0f;
      As[ka][ja + 1] = (e0.y > 0.5) ? 1.0f : 0.0f;
      As[ka][ja + 2] = (e1.x > 0.5) ? 1.0f : 0.0f;
      As[ka][ja + 3] = (e1.y > 0.5) ? 1.0f : 0.0f;
      As[ka][ja + 4] = (e2.x > 0.5) ? 1.0f : 0.0f;
      As[ka][ja + 5] = (e2.y > 0.5) ? 1.0f : 0.0f;
      As[ka][ja + 6] = (e3.x > 0.5) ? 1.0f : 0.0f;
      As[ka][ja + 7] = (e3.y > 0.5) ? 1.0f : 0.0f;
    }
#pragma unroll
    for (int p = 0; p < 4; ++p) {
      int krow = rb + p * 8;
      float4 bv = *reinterpret_cast<const float4*>(Vv + (size_t)(k0 + krow) * 256 + d0 + cbo);
      *reinterpret_cast<float4*>(&Bs[krow][cbo]) = bv;
    }
    __syncthreads();
#pragma unroll
    for (int kk = 0; kk < 32; ++kk) {
      float4 av = *reinterpret_cast<const float4*>(&As[kk][ty * 4]);
      float4 b0 = *reinterpret_cast<const float4*>(&Bs[kk][tx * 8]);
      float4 b1 = *reinterpret_cast<const float4*>(&Bs[kk][tx * 8 + 4]);
      float a_[4] = {av.x, av.y, av.z, av.w};
      float b_[8] = {b0.x, b0.y, b0.z, b0.w, b1.x, b1.y, b1.z, b1.w};
#pragma unroll
      for (int i = 0; i < 4; ++i)
#pragma unroll
        for (int j = 0; j < 8; ++j) acc[i][j] = fmaf(a_[i], b_[j], acc[i][j]);
    }
    __syncthreads();
  }
#pragma unroll
  for (int i = 0; i < 4; ++i) {
    int row = j0 + ty * 4 + i;
    float sc = inv[row];
    size_t base = (size_t)row * 256 + d0 + tx * 8;
    float4 o0 = {acc[i][0] * sc, acc[i][1] * sc, acc[i][2] * sc, acc[i][3] * sc};
    float4 o1 = {acc[i][4] * sc, acc[i][5] * sc, acc[i][6] * sc, acc[i][7] * sc};
    *reinterpret_cast<float4*>(O + base) = o0;
    *reinterpret_cast<float4*>(O + base + 4) = o1;
  }
}

extern "C" void kernel_launch(void* const* d_in, const int* in_sizes, int n_in,
                              void* d_out, int out_size, void* d_ws, size_t ws_size,
                              hipStream_t stream)
{
  const float* Q = (const float*)d_in[0];   // (8,1024,256)
  const float* V = (const float*)d_in[1];   // (8,1024,256)
  float* out = (float*)d_out;               // (8,1024,256)
  char* ws = (char*)d_ws;

  // workspace layout (bytes) — total ~184.6 MB (within known-good 193 MB)
  const size_t OFF_E    = 0;                 // e state, f64 (8,1024,1024)  67MB
  const size_t OFF_P    = 67108864;          // P, f64 (8,1024,1024)        67MB
  const size_t SCR      = 134217728;         // prologue scratch / w_part overlay
  const size_t OFF_G    = SCR;
  const size_t OFF_AD   = SCR + 4194304;
  const size_t OFF_X    = SCR + 8388608;
  const size_t OFF_Y    = SCR + 12582912;
  const size_t OFF_X2   = SCR + 16777216;    // final M (dead before iterations)
  const size_t OFF_PV64 = SCR;               // f64 (8,256,1024) overlays G..Y
  const size_t OFF_WP   = SCR;               // w_part fp32 [4][8][256][1024] 33.5MB (iters only)
  const size_t OFF_W1   = 167772160;         // fp32 W1 (8,256,1024)  8MB
  const size_t OFF_PVP  = 176160768;         // fp32 Pvp (8,256,1024) 8MB
  const size_t OFF_INV  = 184549376;         // fp32 (8,1024)

  double* E    = (double*)(ws + OFF_E);
  double* P    = (double*)(ws + OFF_P);
  double* G    = (double*)(ws + OFF_G);
  double* Ad   = (double*)(ws + OFF_AD);
  double* X    = (double*)(ws + OFF_X);
  double* Y    = (double*)(ws + OFF_Y);
  double* X2   = (double*)(ws + OFF_X2);
  double* PV64 = (double*)(ws + OFF_PV64);
  float*  WP   = (float*)(ws + OFF_WP);
  float*  W1   = (float*)(ws + OFF_W1);
  float*  PVP  = (float*)(ws + OFF_PVP);
  float*  INV  = (float*)(ws + OFF_INV);

  (void)in_sizes; (void)n_in; (void)out_size; (void)ws_size;

  // e = 0
  hipMemsetAsync(ws + OFF_E, 0, 67108864, stream);

  // P = (-2/1024) * V @ Q^T + 0.1/1024     (f64, K=256)
  k_gemm_nt<float, double><<<dim3(16, 16, 8), 256, 0, stream>>>(
      V, Q, P, 1024, 1024, 256, 262144, 262144, 1048576, -2.0 / 1024.0, 0.1 / 1024.0);

  // G = (1/1024^2) V^T @ V   (f64, 256x256)
  k_gemm_tn<float><<<dim3(4, 4, 8), 256, 0, stream>>>(
      V, V, G, 256, 256, 1024, 262144, 262144, 65536, 1.0 / 1048576.0);

  // Ad = I + 2G, X0 = I - 2G
  k_adx0<<<dim3(2048), 256, 0, stream>>>(G, Ad, X);

  // Newton-Schulz x3: X <- X(2I - Ad X); final M in X2
  for (int it = 0; it < 3; ++it) {
    const double* Xc = (it % 2 == 0) ? X : X2;
    double* Xn = (it % 2 == 0) ? X2 : X;
    k_smallmm<false><<<dim3(4, 4, 8), 256, 0, stream>>>(
        Ad, Xc, (const double*)nullptr, (void*)Y, 256, 65536, 65536, 1.0, 0.0);
    k_smallmm<false><<<dim3(4, 4, 8), 256, 0, stream>>>(
        Xc, Y, Xc, (void*)Xn, 256, 65536, 65536, -1.0, 2.0);
  }

  // PV64 = (1/1024) V^T @ P   (f64, 256x1024)
  k_gemm_tn<double><<<dim3(4, 16, 8), 256, 0, stream>>>(
      V, P, PV64, 256, 1024, 1024, 262144, 1048576, 262144, 1.0 / 1024.0);

  // PVP = M @ PV64  (fp32 out)
  k_smallmm<true><<<dim3(4, 16, 8), 256, 0, stream>>>(
      X2, PV64, (const double*)nullptr, (void*)PVP, 1024, 262144, 262144, 1.0, 0.0);

  // W1 = (1/1024) M @ V^T  (fp32 out, 256x1024)
  k_gemm_nt<double, float><<<dim3(4, 16, 8), 256, 0, stream>>>(
      X2, V, W1, 256, 1024, 256, 65536, 262144, 262144, 1.0 / 1024.0, 0.0);

  // 50 ADMM iterations: 2 dispatches/iter, both 1024 blocks (4 blocks/CU)
  for (int t = 0; t < 50; ++t) {
    k_iterA3<<<dim3(4, 8, 32), 256, 0, stream>>>(W1, E, WP);
    k_iterC3<<<dim3(16, 8, 8), 256, 0, stream>>>(V, WP, PVP, P, E);
  }

  // epilogue
  k_count<<<dim3(4, 8), 256, 0, stream>>>(E, INV);
  k_out<<<dim3(16, 2, 8), 256, 0, stream>>>(E, V, INV, out);
}

// Round 8
// 8356.933 us; speedup vs baseline: 1.9239x; 1.2510x over previous
//
#include <hip/hip_runtime.h>

// Problem constants (b=8, n=1024, m=1024, d=256, RHO=1, LAMBDA=0.1, 50 iters)
// ADMM box-QP via Woodbury on A = I + 2 Vs Vs^T  (Vs = V / 1024).
//   state e (f64):  z = clip(e), s = 2z - e  (s materialized fp32 by iterC)
//   w  = W1 @ s - Pvp            (fp32 GEMM, K=1024)   W1 = M Vs^T, Pvp = M Vs^T P
//   e' = clip(e) - P - (2/1024) * (V @ w)   (fp32 GEMM K=256 + f64 elementwise)
// R8 = R1 iteration kernels (bitwise-proven) + XCD-pinned block mapping:
// grid flattened so linear bid % 8 == batch -> per-batch slabs stay in one L2.

__device__ __forceinline__ double clip01(double v) { return fmin(fmax(v, 0.0), 1.0); }

// ---------------- NT GEMM, f64 accumulate: C = (TC)(alpha * A@B^T + c0) ----------
template <typename TA, typename TC>
__global__ __launch_bounds__(256) void k_gemm_nt(
    const TA* __restrict__ Ag, const float* __restrict__ Bg, TC* __restrict__ Cg,
    int M, int N, int K, long sA, long sB, long sC, double alpha, double c0)
{
  const TA* A = Ag + (long)blockIdx.z * sA;
  const float* B = Bg + (long)blockIdx.z * sB;
  TC* C = Cg + (long)blockIdx.z * sC;
  const int m0 = blockIdx.x * 64, n0 = blockIdx.y * 64;
  const int tid = threadIdx.x;
  __shared__ double As[32][68];
  __shared__ double Bs[32][68];
  const int tx = tid & 15, ty = tid >> 4;
  const int r = tid >> 2, kq = (tid & 3) * 8;
  double acc[4][4] = {};
  for (int k0 = 0; k0 < K; k0 += 32) {
    if constexpr (sizeof(TA) == 4) {
      const float4* ap = reinterpret_cast<const float4*>(A + (size_t)(m0 + r) * K + k0 + kq);
      float4 a0 = ap[0], a1 = ap[1];
      As[kq+0][r] = a0.x; As[kq+1][r] = a0.y; As[kq+2][r] = a0.z; As[kq+3][r] = a0.w;
      As[kq+4][r] = a1.x; As[kq+5][r] = a1.y; As[kq+6][r] = a1.z; As[kq+7][r] = a1.w;
    } else {
      const double2* ap = reinterpret_cast<const double2*>(A + (size_t)(m0 + r) * K + k0 + kq);
      double2 a0 = ap[0], a1 = ap[1], a2 = ap[2], a3 = ap[3];
      As[kq+0][r] = a0.x; As[kq+1][r] = a0.y; As[kq+2][r] = a1.x; As[kq+3][r] = a1.y;
      As[kq+4][r] = a2.x; As[kq+5][r] = a2.y; As[kq+6][r] = a3.x; As[kq+7][r] = a3.y;
    }
    {
      const float4* bp = reinterpret_cast<const float4*>(B + (size_t)(n0 + r) * K + k0 + kq);
      float4 b0 = bp[0], b1 = bp[1];
      Bs[kq+0][r] = b0.x; Bs[kq+1][r] = b0.y; Bs[kq+2][r] = b0.z; Bs[kq+3][r] = b0.w;
      Bs[kq+4][r] = b1.x; Bs[kq+5][r] = b1.y; Bs[kq+6][r] = b1.z; Bs[kq+7][r] = b1.w;
    }
    __syncthreads();
#pragma unroll
    for (int kk = 0; kk < 32; ++kk) {
      double a_[4], b_[4];
#pragma unroll
      for (int i = 0; i < 4; ++i) a_[i] = As[kk][ty * 4 + i];
#pragma unroll
      for (int j = 0; j < 4; ++j) b_[j] = Bs[kk][tx * 4 + j];
#pragma unroll
      for (int i = 0; i < 4; ++i)
#pragma unroll
        for (int j = 0; j < 4; ++j) acc[i][j] = fma(a_[i], b_[j], acc[i][j]);
    }
    __syncthreads();
  }
#pragma unroll
  for (int i = 0; i < 4; ++i) {
    int row = m0 + ty * 4 + i;
#pragma unroll
    for (int j = 0; j < 4; ++j)
      C[(size_t)row * N + n0 + tx * 4 + j] = (TC)(alpha * acc[i][j] + c0);
  }
}

// ---------------- TN GEMM, f64 accumulate: C[MxN] = scale * A^T @ B -------------
template <typename TB>
__global__ __launch_bounds__(256) void k_gemm_tn(
    const float* __restrict__ Ag, const TB* __restrict__ Bg, double* __restrict__ Cg,
    int M, int N, int K, long sA, long sB, long sC, double scale)
{
  const float* A = Ag + (long)blockIdx.z * sA;
  const TB* B = Bg + (long)blockIdx.z * sB;
  double* C = Cg + (long)blockIdx.z * sC;
  const int m0 = blockIdx.x * 64, n0 = blockIdx.y * 64;
  const int tid = threadIdx.x;
  __shared__ float As[16][68];
  __shared__ double Bs[16][68];
  const int tx = tid & 15, ty = tid >> 4;
  const int kk = tid >> 4, c4 = (tid & 15) * 4;
  double acc[4][4] = {};
  for (int k0 = 0; k0 < K; k0 += 16) {
    float4 av = *reinterpret_cast<const float4*>(A + (size_t)(k0 + kk) * M + m0 + c4);
    *reinterpret_cast<float4*>(&As[kk][c4]) = av;
    if constexpr (sizeof(TB) == 4) {
      float4 bv = *reinterpret_cast<const float4*>(B + (size_t)(k0 + kk) * N + n0 + c4);
      Bs[kk][c4 + 0] = bv.x; Bs[kk][c4 + 1] = bv.y; Bs[kk][c4 + 2] = bv.z; Bs[kk][c4 + 3] = bv.w;
    } else {
      const double2* bp = reinterpret_cast<const double2*>(B + (size_t)(k0 + kk) * N + n0 + c4);
      double2 b0 = bp[0], b1 = bp[1];
      *reinterpret_cast<double2*>(&Bs[kk][c4]) = b0;
      *reinterpret_cast<double2*>(&Bs[kk][c4 + 2]) = b1;
    }
    __syncthreads();
#pragma unroll
    for (int k = 0; k < 16; ++k) {
      double a_[4], b_[4];
#pragma unroll
      for (int i = 0; i < 4; ++i) a_[i] = (double)As[k][ty * 4 + i];
#pragma unroll
      for (int j = 0; j < 4; ++j) b_[j] = Bs[k][tx * 4 + j];
#pragma unroll
      for (int i = 0; i < 4; ++i)
#pragma unroll
        for (int j = 0; j < 4; ++j) acc[i][j] = fma(a_[i], b_[j], acc[i][j]);
    }
    __syncthreads();
  }
#pragma unroll
  for (int i = 0; i < 4; ++i) {
    int row = m0 + ty * 4 + i;
#pragma unroll
    for (int j = 0; j < 4; ++j)
      C[(size_t)row * N + n0 + tx * 4 + j] = scale * acc[i][j];
  }
}

// ---------------- Ad = I + 2G, X0 = I - 2G --------------------------------------
__global__ __launch_bounds__(256) void k_adx0(const double* __restrict__ G,
                                              double* __restrict__ Ad, double* __restrict__ X)
{
  size_t idx = (size_t)blockIdx.x * 256 + threadIdx.x;
  double g = G[idx];
  int ij = (int)(idx & 65535);
  double dg = ((ij >> 8) == (ij & 255)) ? 1.0 : 0.0;
  Ad[idx] = dg + 2.0 * g;
  X[idx] = dg - 2.0 * g;
}

// ---------------- small f64 NN GEMM: C = alpha*A@B + beta*Xin -------------------
template <bool F32OUT>
__global__ __launch_bounds__(256) void k_smallmm(
    const double* __restrict__ Ag, const double* __restrict__ Bg,
    const double* __restrict__ Xg, void* __restrict__ Cg,
    int N, long sB, long sC, double alpha, double beta)
{
  const double* A = Ag + (long)blockIdx.z * 65536;
  const double* B = Bg + (long)blockIdx.z * sB;
  const double* Xp = Xg ? (Xg + (long)blockIdx.z * sB) : (const double*)nullptr;
  const int m0 = blockIdx.x * 64, n0 = blockIdx.y * 64;
  const int tid = threadIdx.x;
  __shared__ double As[16][68];
  __shared__ double Bs[16][68];
  const int tx = tid & 15, ty = tid >> 4;
  const int ra = tid >> 2, kqa = (tid & 3) * 4;
  const int kb = tid >> 4, cb = (tid & 15) * 4;
  double acc[4][4] = {};
  for (int k0 = 0; k0 < 256; k0 += 16) {
    const double2* ap = reinterpret_cast<const double2*>(A + (size_t)(m0 + ra) * 256 + k0 + kqa);
    double2 a0 = ap[0], a1 = ap[1];
    As[kqa + 0][ra] = a0.x; As[kqa + 1][ra] = a0.y; As[kqa + 2][ra] = a1.x; As[kqa + 3][ra] = a1.y;
    const double2* bp = reinterpret_cast<const double2*>(B + (size_t)(k0 + kb) * N + n0 + cb);
    double2 b0 = bp[0], b1 = bp[1];
    *reinterpret_cast<double2*>(&Bs[kb][cb]) = b0;
    *reinterpret_cast<double2*>(&Bs[kb][cb + 2]) = b1;
    __syncthreads();
#pragma unroll
    for (int k = 0; k < 16; ++k) {
      double a_[4], b_[4];
#pragma unroll
      for (int i = 0; i < 4; ++i) a_[i] = As[k][ty * 4 + i];
#pragma unroll
      for (int j = 0; j < 4; ++j) b_[j] = Bs[k][tx * 4 + j];
#pragma unroll
      for (int i = 0; i < 4; ++i)
#pragma unroll
        for (int j = 0; j < 4; ++j) acc[i][j] = fma(a_[i], b_[j], acc[i][j]);
    }
    __syncthreads();
  }
#pragma unroll
  for (int i = 0; i < 4; ++i) {
    int row = m0 + ty * 4 + i;
#pragma unroll
    for (int j = 0; j < 4; ++j) {
      int col = n0 + tx * 4 + j;
      double v = alpha * acc[i][j];
      if (beta != 0.0) v = fma(beta, Xp[(size_t)row * N + col], v);
      if constexpr (F32OUT)
        ((float*)Cg)[(long)blockIdx.z * sC + (size_t)row * N + col] = (float)v;
      else
        ((double*)Cg)[(long)blockIdx.z * sC + (size_t)row * N + col] = v;
    }
  }
}

// ---------------- per-iter GEMM A (fp32): w = W1 @ s - Pvp ----------------------
// W1: (256x1024), s: (1024x1024), w/Pvp: (256x1024). BM=64,BN=128,BK=32, micro 4x8.
// grid (32, 8): x = mt*8 + b  (bid%8 == b -> XCD-pinned), y = nt.
__global__ __launch_bounds__(256) void k_iterA5(
    const float* __restrict__ W1g, const float* __restrict__ Sg,
    const float* __restrict__ Pvg, float* __restrict__ Wg)
{
  const int b = blockIdx.x & 7, mt = blockIdx.x >> 3;
  const float* A = W1g + (size_t)b * 262144;
  const float* B = Sg + (size_t)b * 1048576;
  const float* Pv = Pvg + (size_t)b * 262144;
  float* C = Wg + (size_t)b * 262144;
  const int m0 = mt * 64, n0 = blockIdx.y * 128;
  const int tid = threadIdx.x;
  __shared__ float As[32][68];
  __shared__ float Bs[32][132];
  const int tx = tid & 15, ty = tid >> 4;
  const int ra = tid >> 2, kqa = (tid & 3) * 8;
  const int rb = tid >> 5, cb = (tid & 31) * 4;
  float acc[4][8] = {};
  for (int k0 = 0; k0 < 1024; k0 += 32) {
    {
      const float4* ap = reinterpret_cast<const float4*>(A + (size_t)(m0 + ra) * 1024 + k0 + kqa);
      float4 a0 = ap[0], a1 = ap[1];
      As[kqa + 0][ra] = a0.x; As[kqa + 1][ra] = a0.y; As[kqa + 2][ra] = a0.z; As[kqa + 3][ra] = a0.w;
      As[kqa + 4][ra] = a1.x; As[kqa + 5][ra] = a1.y; As[kqa + 6][ra] = a1.z; As[kqa + 7][ra] = a1.w;
    }
#pragma unroll
    for (int p = 0; p < 4; ++p) {
      int krow = rb + p * 8;
      float4 bv = *reinterpret_cast<const float4*>(B + (size_t)(k0 + krow) * 1024 + n0 + cb);
      *reinterpret_cast<float4*>(&Bs[krow][cb]) = bv;
    }
    __syncthreads();
#pragma unroll
    for (int kk = 0; kk < 32; ++kk) {
      float4 av = *reinterpret_cast<const float4*>(&As[kk][ty * 4]);
      float4 b0 = *reinterpret_cast<const float4*>(&Bs[kk][tx * 8]);
      float4 b1 = *reinterpret_cast<const float4*>(&Bs[kk][tx * 8 + 4]);
      float a_[4] = {av.x, av.y, av.z, av.w};
      float b_[8] = {b0.x, b0.y, b0.z, b0.w, b1.x, b1.y, b1.z, b1.w};
#pragma unroll
      for (int i = 0; i < 4; ++i)
#pragma unroll
        for (int j = 0; j < 8; ++j) acc[i][j] = fmaf(a_[i], b_[j], acc[i][j]);
    }
    __syncthreads();
  }
#pragma unroll
  for (int i = 0; i < 4; ++i) {
    size_t base = (size_t)(m0 + ty * 4 + i) * 1024 + n0 + tx * 8;
    float4 p0 = *reinterpret_cast<const float4*>(Pv + base);
    float4 p1 = *reinterpret_cast<const float4*>(Pv + base + 4);
    float4 o0, o1;
    o0.x = acc[i][0] - p0.x; o0.y = acc[i][1] - p0.y; o0.z = acc[i][2] - p0.z; o0.w = acc[i][3] - p0.w;
    o1.x = acc[i][4] - p1.x; o1.y = acc[i][5] - p1.y; o1.z = acc[i][6] - p1.z; o1.w = acc[i][7] - p1.w;
    *reinterpret_cast<float4*>(C + base) = o0;
    *reinterpret_cast<float4*>(C + base + 4) = o1;
  }
}

// ---------------- per-iter fused GEMM C + elementwise ---------------------------
// g = V @ w ; e' = clip(e) - P - (2/1024)*g ; s' = 2*clip(e') - e' (fp32)
// V: (1024x256), w: (256x1024), e/P: (1024x1024) f64. BM=BN=128, BK=16, micro 8x8.
// grid (64, 8): x = mt*8 + b  (bid%8 == b -> XCD-pinned), y = nt.
__global__ __launch_bounds__(256) void k_iterC5(
    const float* __restrict__ Vg, const float* __restrict__ Wg,
    const double* __restrict__ Pg, double* __restrict__ Eg, float* __restrict__ Sg)
{
  const int b = blockIdx.x & 7, mt = blockIdx.x >> 3;
  const float* A = Vg + (size_t)b * 262144;
  const float* B = Wg + (size_t)b * 262144;
  const double* P = Pg + (size_t)b * 1048576;
  double* E = Eg + (size_t)b * 1048576;
  float* S = Sg + (size_t)b * 1048576;
  const int m0 = mt * 128, n0 = blockIdx.y * 128;
  const int tid = threadIdx.x;
  __shared__ float As[16][132];
  __shared__ float Bs[16][132];
  const int tx = tid & 15, ty = tid >> 4;
  const int ra = tid >> 1, kqa = (tid & 1) * 8;
  const int rb = tid >> 5, cb = (tid & 31) * 4;
  float acc[8][8] = {};
  for (int k0 = 0; k0 < 256; k0 += 16) {
    {
      const float4* ap = reinterpret_cast<const float4*>(A + (size_t)(m0 + ra) * 256 + k0 + kqa);
      float4 a0 = ap[0], a1 = ap[1];
      As[kqa + 0][ra] = a0.x; As[kqa + 1][ra] = a0.y; As[kqa + 2][ra] = a0.z; As[kqa + 3][ra] = a0.w;
      As[kqa + 4][ra] = a1.x; As[kqa + 5][ra] = a1.y; As[kqa + 6][ra] = a1.z; As[kqa + 7][ra] = a1.w;
    }
#pragma unroll
    for (int p = 0; p < 2; ++p) {
      int krow = rb + p * 8;
      float4 bv = *reinterpret_cast<const float4*>(B + (size_t)(k0 + krow) * 1024 + n0 + cb);
      *reinterpret_cast<float4*>(&Bs[krow][cb]) = bv;
    }
    __syncthreads();
#pragma unroll
    for (int kk = 0; kk < 16; ++kk) {
      float4 a0 = *reinterpret_cast<const float4*>(&As[kk][ty * 8]);
      float4 a1 = *reinterpret_cast<const float4*>(&As[kk][ty * 8 + 4]);
      float4 b0 = *reinterpret_cast<const float4*>(&Bs[kk][tx * 8]);
      float4 b1 = *reinterpret_cast<const float4*>(&Bs[kk][tx * 8 + 4]);
      float a_[8] = {a0.x, a0.y, a0.z, a0.w, a1.x, a1.y, a1.z, a1.w};
      float b_[8] = {b0.x, b0.y, b0.z, b0.w, b1.x, b1.y, b1.z, b1.w};
#pragma unroll
      for (int i = 0; i < 8; ++i)
#pragma unroll
        for (int j = 0; j < 8; ++j) acc[i][j] = fmaf(a_[i], b_[j], acc[i][j]);
    }
    __syncthreads();
  }
  const double cg = 2.0 / 1024.0;
#pragma unroll
  for (int ii = 0; ii < 8; ++ii) {
    size_t base = (size_t)(m0 + ty * 8 + ii) * 1024 + n0 + tx * 8;
    double e_[8], p_[8];
#pragma unroll
    for (int q = 0; q < 4; ++q) {
      double2 ev = *reinterpret_cast<const double2*>(E + base + 2 * q);
      double2 pv = *reinterpret_cast<const double2*>(P + base + 2 * q);
      e_[2 * q] = ev.x; e_[2 * q + 1] = ev.y;
      p_[2 * q] = pv.x; p_[2 * q + 1] = pv.y;
    }
    float s_[8];
#pragma unroll
    for (int j = 0; j < 8; ++j) {
      double z = clip01(e_[j]);
      double en = z - p_[j] - cg * (double)acc[ii][j];
      e_[j] = en;
      s_[j] = (float)(2.0 * clip01(en) - en);
    }
#pragma unroll
    for (int q = 0; q < 4; ++q) {
      double2 ev; ev.x = e_[2 * q]; ev.y = e_[2 * q + 1];
      *reinterpret_cast<double2*>(E + base + 2 * q) = ev;
    }
    float4 s0 = {s_[0], s_[1], s_[2], s_[3]}, s1 = {s_[4], s_[5], s_[6], s_[7]};
    *reinterpret_cast<float4*>(S + base) = s0;
    *reinterpret_cast<float4*>(S + base + 4) = s1;
  }
}

// ---------------- per-(b,n) count -> inverse scale ------------------------------
__global__ __launch_bounds__(256) void k_count(const double* __restrict__ Eg, float* __restrict__ inv)
{
  const int bz = blockIdx.y;
  const int j = blockIdx.x * 256 + threadIdx.x;
  const double* E = Eg + (size_t)bz * 1048576;
  int c = 0;
  for (int i = 0; i < 1024; ++i) c += (E[(size_t)i * 1024 + j] > 0.5) ? 1 : 0;
  inv[bz * 1024 + j] = (float)(1.0 / (((double)c) + 1e-10) / 1024.0);
}

// ---------------- output masked GEMM: out[j,dd] = inv[j] * sum_i mask(e) V[i,dd] --
__global__ __launch_bounds__(256) void k_out(
    const double* __restrict__ Eg, const float* __restrict__ Vg,
    const float* __restrict__ invg, float* __restrict__ Og)
{
  const double* E = Eg + (size_t)blockIdx.z * 1048576;
  const float* Vv = Vg + (size_t)blockIdx.z * 262144;
  const float* inv = invg + blockIdx.z * 1024;
  float* O = Og + (size_t)blockIdx.z * 262144;
  const int j0 = blockIdx.x * 64, d0 = blockIdx.y * 128;
  const int tid = threadIdx.x;
  __shared__ float As[32][68];
  __shared__ float Bs[32][132];
  const int tx = tid & 15, ty = tid >> 4;
  const int ka = tid >> 3, ja = (tid & 7) * 8;
  const int rb = tid >> 5, cbo = (tid & 31) * 4;
  float acc[4][8] = {};
  for (int k0 = 0; k0 < 1024; k0 += 32) {
    {
      const double2* ep = reinterpret_cast<const double2*>(E + (size_t)(k0 + ka) * 1024 + j0 + ja);
      double2 e0 = ep[0], e1 = ep[1], e2 = ep[2], e3 = ep[3];
      As[ka][ja + 0] = (e0.x > 0.5) ? 1.0f : 0.0f;
      As[ka][ja + 1] = (e0.y > 0.5) ? 1.0f : 0.0f;
      As[ka][ja + 2] = (e1.x > 0.5) ? 1.0f : 0.0f;
      As[ka][ja + 3] = (e1.y > 0.5) ? 1.0f : 0.0f;
      As[ka][ja + 4] = (e2.x > 0.5) ? 1.0f : 0.0f;
      As[ka][ja + 5] = (e2.y > 0.5) ? 1.0f : 0.0f;
      As[ka][ja + 6] = (e3.x > 0.5) ? 1.0f : 0.0f;
      As[ka][ja + 7] = (e3.y > 0.5) ? 1.0f : 0.0f;
    }
#pragma unroll
    for (int p = 0; p < 4; ++p) {
      int krow = rb + p * 8;
      float4 bv = *reinterpret_cast<const float4*>(Vv + (size_t)(k0 + krow) * 256 + d0 + cbo);
      *reinterpret_cast<float4*>(&Bs[krow][cbo]) = bv;
    }
    __syncthreads();
#pragma unroll
    for (int kk = 0; kk < 32; ++kk) {
      float4 av = *reinterpret_cast<const float4*>(&As[kk][ty * 4]);
      float4 b0 = *reinterpret_cast<const float4*>(&Bs[kk][tx * 8]);
      float4 b1 = *reinterpret_cast<const float4*>(&Bs[kk][tx * 8 + 4]);
      float a_[4] = {av.x, av.y, av.z, av.w};
      float b_[8] = {b0.x, b0.y, b0.z, b0.w, b1.x, b1.y, b1.z, b1.w};
#pragma unroll
      for (int i = 0; i < 4; ++i)
#pragma unroll
        for (int j = 0; j < 8; ++j) acc[i][j] = fmaf(a_[i], b_[j], acc[i][j]);
    }
    __syncthreads();
  }
#pragma unroll
  for (int i = 0; i < 4; ++i) {
    int row = j0 + ty * 4 + i;
    float sc = inv[row];
    size_t base = (size_t)row * 256 + d0 + tx * 8;
    float4 o0 = {acc[i][0] * sc, acc[i][1] * sc, acc[i][2] * sc, acc[i][3] * sc};
    float4 o1 = {acc[i][4] * sc, acc[i][5] * sc, acc[i][6] * sc, acc[i][7] * sc};
    *reinterpret_cast<float4*>(O + base) = o0;
    *reinterpret_cast<float4*>(O + base + 4) = o1;
  }
}

extern "C" void kernel_launch(void* const* d_in, const int* in_sizes, int n_in,
                              void* d_out, int out_size, void* d_ws, size_t ws_size,
                              hipStream_t stream)
{
  const float* Q = (const float*)d_in[0];   // (8,1024,256)
  const float* V = (const float*)d_in[1];   // (8,1024,256)
  float* out = (float*)d_out;               // (8,1024,256)
  char* ws = (char*)d_ws;

  // workspace layout (bytes) — total ~193 MB (identical to round 1)
  const size_t OFF_E   = 0;                  // e state, f64 (8,1024,1024)   67MB
  const size_t OFF_P   = 67108864;           // P, f64 (8,1024,1024)         67MB
  const size_t SCR     = 134217728;          // scratch region (33.5 MB)
  const size_t OFF_G   = SCR;
  const size_t OFF_AD  = SCR + 4194304;
  const size_t OFF_X   = SCR + 8388608;
  const size_t OFF_Y   = SCR + 12582912;
  const size_t OFF_X2  = SCR + 16777216;     // final M
  const size_t OFF_PV64= SCR;                // f64 (8,256,1024) overlays G..Y
  const size_t OFF_S32 = SCR;                // fp32 s (8,1024,1024) overlays scratch
  const size_t OFF_W   = 167772160;          // fp32 w (8,256,1024)
  const size_t OFF_W1  = 176160768;          // fp32 W1 (8,256,1024)
  const size_t OFF_PVP = 184549376;          // fp32 Pvp (8,256,1024)
  const size_t OFF_INV = 192937984;          // fp32 (8,1024)

  double* E    = (double*)(ws + OFF_E);
  double* P    = (double*)(ws + OFF_P);
  double* G    = (double*)(ws + OFF_G);
  double* Ad   = (double*)(ws + OFF_AD);
  double* X    = (double*)(ws + OFF_X);
  double* Y    = (double*)(ws + OFF_Y);
  double* X2   = (double*)(ws + OFF_X2);
  double* PV64 = (double*)(ws + OFF_PV64);
  float*  S32  = (float*)(ws + OFF_S32);
  float*  W    = (float*)(ws + OFF_W);
  float*  W1   = (float*)(ws + OFF_W1);
  float*  PVP  = (float*)(ws + OFF_PVP);
  float*  INV  = (float*)(ws + OFF_INV);

  (void)in_sizes; (void)n_in; (void)out_size; (void)ws_size;

  // e = 0
  hipMemsetAsync(ws + OFF_E, 0, 67108864, stream);

  // P = (-2/1024) * V @ Q^T + 0.1/1024     (f64, K=256)
  k_gemm_nt<float, double><<<dim3(16, 16, 8), 256, 0, stream>>>(
      V, Q, P, 1024, 1024, 256, 262144, 262144, 1048576, -2.0 / 1024.0, 0.1 / 1024.0);

  // G = (1/1024^2) V^T @ V   (f64, 256x256)
  k_gemm_tn<float><<<dim3(4, 4, 8), 256, 0, stream>>>(
      V, V, G, 256, 256, 1024, 262144, 262144, 65536, 1.0 / 1048576.0);

  // Ad = I + 2G, X0 = I - 2G
  k_adx0<<<dim3(2048), 256, 0, stream>>>(G, Ad, X);

  // Newton-Schulz x3: X <- X(2I - Ad X); final M in X2
  for (int it = 0; it < 3; ++it) {
    const double* Xc = (it % 2 == 0) ? X : X2;
    double* Xn = (it % 2 == 0) ? X2 : X;
    k_smallmm<false><<<dim3(4, 4, 8), 256, 0, stream>>>(
        Ad, Xc, (const double*)nullptr, (void*)Y, 256, 65536, 65536, 1.0, 0.0);
    k_smallmm<false><<<dim3(4, 4, 8), 256, 0, stream>>>(
        Xc, Y, Xc, (void*)Xn, 256, 65536, 65536, -1.0, 2.0);
  }

  // PV64 = (1/1024) V^T @ P   (f64, 256x1024)
  k_gemm_tn<double><<<dim3(4, 16, 8), 256, 0, stream>>>(
      V, P, PV64, 256, 1024, 1024, 262144, 1048576, 262144, 1.0 / 1024.0);

  // PVP = M @ PV64  (fp32 out)
  k_smallmm<true><<<dim3(4, 16, 8), 256, 0, stream>>>(
      X2, PV64, (const double*)nullptr, (void*)PVP, 1024, 262144, 262144, 1.0, 0.0);

  // W1 = (1/1024) M @ V^T  (fp32 out, 256x1024)
  k_gemm_nt<double, float><<<dim3(4, 16, 8), 256, 0, stream>>>(
      X2, V, W1, 256, 1024, 256, 65536, 262144, 262144, 1.0 / 1024.0, 0.0);

  // s = 0  (overlays scratch; PV64/X2 now dead)
  hipMemsetAsync(ws + OFF_S32, 0, 33554432, stream);

  // 50 ADMM iterations (XCD-pinned grids: bid%8 == batch)
  for (int t = 0; t < 50; ++t) {
    k_iterA5<<<dim3(32, 8), 256, 0, stream>>>(W1, S32, PVP, W);
    k_iterC5<<<dim3(64, 8), 256, 0, stream>>>(V, W, P, E, S32);
  }

  // epilogue
  k_count<<<dim3(4, 8), 256, 0, stream>>>(E, INV);
  k_out<<<dim3(16, 2, 8), 256, 0, stream>>>(E, V, INV, out);
}